// Round 1
// baseline (326.049 us; speedup 1.0000x reference)
//
#include <hip/hip_runtime.h>

#define T_TOKENS 16384
#define CAP 12288   // per-expert bucket capacity; expected count ~4096 (binomial, 60σ margin)

typedef unsigned short u16;
typedef __attribute__((ext_vector_type(8))) short short8;
typedef __attribute__((ext_vector_type(4))) float float4v;

__device__ __forceinline__ u16 f2b(float f) {
  unsigned u = __float_as_uint(f);
  u = (u + 0x7fffu + ((u >> 16) & 1u)) >> 16;   // RNE fp32 -> bf16
  return (u16)u;
}
__device__ __forceinline__ float b2f(u16 h) {
  return __uint_as_float(((unsigned)h) << 16);
}

// ---------------- weight fp32 -> bf16 conversion ----------------
__global__ void convert_w(const float* __restrict__ W1, const float* __restrict__ W2,
                          const float* __restrict__ W3, u16* __restrict__ Wb1,
                          u16* __restrict__ Wb2, u16* __restrict__ Wb3) {
  const int n1 = 8 * 256 * 512, n2 = 8 * 256 * 256;
  int base = (blockIdx.x * 256 + threadIdx.x) * 8;
  const float* src;
  u16* dst;
  int off = base;
  if (base < n1) { src = W1; dst = Wb1; }
  else if (base < n1 + n2) { src = W2; dst = Wb2; off = base - n1; }
  else { src = W3; dst = Wb3; off = base - n1 - n2; }
  float4 a0 = *(const float4*)(src + off);
  float4 a1 = *(const float4*)(src + off + 4);
  short8 v;
  v[0] = (short)f2b(a0.x); v[1] = (short)f2b(a0.y);
  v[2] = (short)f2b(a0.z); v[3] = (short)f2b(a0.w);
  v[4] = (short)f2b(a1.x); v[5] = (short)f2b(a1.y);
  v[6] = (short)f2b(a1.z); v[7] = (short)f2b(a1.w);
  *(short8*)(dst + off) = v;
}

// ---------------- routing: bucket (t,k) pairs per expert, per stage ----------------
__global__ void route_kernel(const int* __restrict__ m1, const int* __restrict__ m2,
                             const int* __restrict__ m3, const float* __restrict__ rw1,
                             const float* __restrict__ rw2, const float* __restrict__ rw3,
                             int* __restrict__ cnt, int* __restrict__ idxbuf,
                             float* __restrict__ wgtbuf) {
  int t = blockIdx.x * 256 + threadIdx.x;     // grid exactly covers T: all lanes active
  int lane = threadIdx.x & 63;
  const int* masks[3] = {m1, m2, m3};
  const float* rws[3] = {rw1, rw2, rw3};
#pragma unroll
  for (int s = 0; s < 3; ++s) {
#pragma unroll
    for (int k = 0; k < 2; ++k) {
      int e = 0;
#pragma unroll
      for (int j = 0; j < 8; ++j)
        if (masks[s][(j * 2 + k) * T_TOKENS + t] != 0) e = j;
      float w = rws[s][t * 2 + k];
      // wave-aggregated bucket append: one atomic per (wave, expert)
#pragma unroll
      for (int j = 0; j < 8; ++j) {
        unsigned long long b = __ballot(e == j);
        if (b != 0ull) {
          int leader = __ffsll(b) - 1;
          int base = 0;
          if (lane == leader) base = atomicAdd(&cnt[s * 8 + j], __popcll(b));
          base = __shfl(base, leader);
          if (e == j) {
            int p = base + __popcll(b & ((1ull << lane) - 1ull));
            if (p < CAP) {
              idxbuf[(s * 8 + j) * CAP + p] = t * 2 + k;
              wgtbuf[(s * 8 + j) * CAP + p] = w;
            }
          }
        }
      }
    }
  }
}

// ---------------- grouped gather-GEMM: 64 rows x 256 cols per block ----------------
// SRC==0: A rows gathered from fp32 x (row length KDIM), converted to bf16.
// SRC==1: A rows = bf16 tmpPrev[t][0][:] + tmpPrev[t][1][:] (fp32 add, re-round).
// Epilogue: out = w * (relu?)(dot + bias), scattered bf16 to outTmp[t*2+k][NDIM_TOTAL].
template <int KDIM, int NDIM_TOTAL, int SRC, int RELU>
__global__ __launch_bounds__(256) void moe_gemm(
    const void* __restrict__ Asrc, const u16* __restrict__ Wb, const float* __restrict__ bias,
    const int* __restrict__ cnt, const int* __restrict__ idxbuf, const float* __restrict__ wgtbuf,
    u16* __restrict__ outTmp) {
  __shared__ __align__(16) u16 As[64][72];    // +8 pad: bank-conflict break
  __shared__ __align__(16) u16 Bs[256][72];
  __shared__ int rowTok[64];
  __shared__ float rowW[64];

  const int e = blockIdx.y;
  const int n_e = cnt[e];
  const int row0 = blockIdx.x * 64;
  if (row0 >= n_e) return;
  const int nbase = blockIdx.z * 256;
  const int tid = threadIdx.x;

  if (tid < 64) {
    int g = row0 + tid;
    if (g < n_e) {
      rowTok[tid] = idxbuf[e * CAP + g];
      rowW[tid] = wgtbuf[e * CAP + g];
    } else {
      rowTok[tid] = 0;   // safe gather target; stores masked by g < n_e
      rowW[tid] = 0.f;
    }
  }
  __syncthreads();

  const int wave = tid >> 6, lane = tid & 63;
  const int lrow = lane & 15, lquad = lane >> 4;
  const int arow = tid >> 3;            // 0..31
  const int acol = (tid & 7) * 8;       // element offset, 16B granules

  float4v acc[4][4];
#pragma unroll
  for (int i = 0; i < 4; ++i)
#pragma unroll
    for (int j = 0; j < 4; ++j) acc[i][j] = (float4v)0.f;

  const u16* Wbe = Wb + ((size_t)e * NDIM_TOTAL + nbase) * KDIM;

  for (int kb = 0; kb < KDIM; kb += 64) {
    // ---- stage A tile (64 x 64) ----
#pragma unroll
    for (int it = 0; it < 2; ++it) {
      int r = arow + it * 32;
      int tok = rowTok[r];
      short8 v;
      if (SRC == 0) {
        const float* xp = (const float*)Asrc + (size_t)(tok >> 1) * KDIM + kb + acol;
        float4 a0 = *(const float4*)xp;
        float4 a1 = *(const float4*)(xp + 4);
        v[0] = (short)f2b(a0.x); v[1] = (short)f2b(a0.y);
        v[2] = (short)f2b(a0.z); v[3] = (short)f2b(a0.w);
        v[4] = (short)f2b(a1.x); v[5] = (short)f2b(a1.y);
        v[6] = (short)f2b(a1.z); v[7] = (short)f2b(a1.w);
      } else {
        const u16* p0 = (const u16*)Asrc + ((size_t)(tok >> 1) * 2) * KDIM + kb + acol;
        short8 v0 = *(const short8*)p0;
        short8 v1 = *(const short8*)(p0 + KDIM);
#pragma unroll
        for (int j = 0; j < 8; ++j)
          v[j] = (short)f2b(b2f((u16)v0[j]) + b2f((u16)v1[j]));
      }
      *(short8*)&As[r][acol] = v;
    }
    // ---- stage B tile (256 x 64) ----
#pragma unroll
    for (int it = 0; it < 8; ++it) {
      int r = arow + it * 32;
      *(short8*)&Bs[r][acol] = *(const short8*)(Wbe + (size_t)r * KDIM + kb + acol);
    }
    __syncthreads();
    // ---- MFMA ----
#pragma unroll
    for (int ks = 0; ks < 64; ks += 32) {
      short8 af[4], bfr[4];
#pragma unroll
      for (int mt = 0; mt < 4; ++mt)
        af[mt] = *(const short8*)&As[mt * 16 + lrow][ks + lquad * 8];
#pragma unroll
      for (int nt = 0; nt < 4; ++nt)
        bfr[nt] = *(const short8*)&Bs[wave * 64 + nt * 16 + lrow][ks + lquad * 8];
#pragma unroll
      for (int mt = 0; mt < 4; ++mt)
#pragma unroll
        for (int nt = 0; nt < 4; ++nt)
          acc[mt][nt] = __builtin_amdgcn_mfma_f32_16x16x32_bf16(af[mt], bfr[nt], acc[mt][nt], 0, 0, 0);
    }
    __syncthreads();
  }

  // ---- epilogue: w * (relu?)(dot + bias) -> scatter bf16 ----
  float bv[4];
#pragma unroll
  for (int nt = 0; nt < 4; ++nt)
    bv[nt] = bias[e * NDIM_TOTAL + nbase + wave * 64 + nt * 16 + lrow];
#pragma unroll
  for (int mt = 0; mt < 4; ++mt) {
#pragma unroll
    for (int i = 0; i < 4; ++i) {
      int m = mt * 16 + lquad * 4 + i;
      if (row0 + m < n_e) {
        float w = rowW[m];
        size_t drow = (size_t)rowTok[m] * NDIM_TOTAL + nbase;
#pragma unroll
        for (int nt = 0; nt < 4; ++nt) {
          float v = acc[mt][nt][i] + bv[nt];
          if (RELU) v = fmaxf(v, 0.f);
          v *= w;
          outTmp[drow + wave * 64 + nt * 16 + lrow] = f2b(v);
        }
      }
    }
  }
}

// ---------------- finalize: out = relu(tmp3[t][0] + tmp3[t][1]) ----------------
__global__ void finalize_kernel(const u16* __restrict__ tmp3, float* __restrict__ out) {
  int f = (blockIdx.x * 256 + threadIdx.x) * 8;
  int t = f >> 9;
  int o = f & 511;
  const u16* p = tmp3 + (size_t)t * 1024 + o;
  short8 v0 = *(const short8*)p;
  short8 v1 = *(const short8*)(p + 512);
  float4 r0, r1;
  r0.x = fmaxf(b2f((u16)v0[0]) + b2f((u16)v1[0]), 0.f);
  r0.y = fmaxf(b2f((u16)v0[1]) + b2f((u16)v1[1]), 0.f);
  r0.z = fmaxf(b2f((u16)v0[2]) + b2f((u16)v1[2]), 0.f);
  r0.w = fmaxf(b2f((u16)v0[3]) + b2f((u16)v1[3]), 0.f);
  r1.x = fmaxf(b2f((u16)v0[4]) + b2f((u16)v1[4]), 0.f);
  r1.y = fmaxf(b2f((u16)v0[5]) + b2f((u16)v1[5]), 0.f);
  r1.z = fmaxf(b2f((u16)v0[6]) + b2f((u16)v1[6]), 0.f);
  r1.w = fmaxf(b2f((u16)v0[7]) + b2f((u16)v1[7]), 0.f);
  *(float4*)(out + f) = r0;
  *(float4*)(out + f + 4) = r1;
}

extern "C" void kernel_launch(void* const* d_in, const int* in_sizes, int n_in,
                              void* d_out, int out_size, void* d_ws, size_t ws_size,
                              hipStream_t stream) {
  const float* x  = (const float*)d_in[0];
  const int* m1   = (const int*)d_in[1];
  const int* m2   = (const int*)d_in[2];
  const int* m3   = (const int*)d_in[3];
  const float* rw1 = (const float*)d_in[4];
  const float* rw2 = (const float*)d_in[5];
  const float* rw3 = (const float*)d_in[6];
  const float* W1 = (const float*)d_in[7];
  const float* b1 = (const float*)d_in[8];
  const float* W2 = (const float*)d_in[9];
  const float* b2 = (const float*)d_in[10];
  const float* W3 = (const float*)d_in[11];
  const float* b3 = (const float*)d_in[12];
  float* out = (float*)d_out;

  char* ws = (char*)d_ws;
  size_t off = 0;
  int* cnt = (int*)(ws + off); off += 256;
  u16* Wb1 = (u16*)(ws + off); off += (size_t)8 * 256 * 512 * 2;
  u16* Wb2 = (u16*)(ws + off); off += (size_t)8 * 256 * 256 * 2;
  u16* Wb3 = (u16*)(ws + off); off += (size_t)8 * 512 * 256 * 2;
  u16* tmp1 = (u16*)(ws + off); off += (size_t)T_TOKENS * 2 * 256 * 2;
  u16* tmp2 = (u16*)(ws + off); off += (size_t)T_TOKENS * 2 * 256 * 2;
  u16* tmp3 = (u16*)(ws + off); off += (size_t)T_TOKENS * 2 * 512 * 2;
  int* idxb = (int*)(ws + off); off += (size_t)3 * 8 * CAP * 4;
  float* wgtb = (float*)(ws + off); off += (size_t)3 * 8 * CAP * 4;

  hipMemsetAsync(cnt, 0, 96, stream);
  convert_w<<<1280, 256, 0, stream>>>(W1, W2, W3, Wb1, Wb2, Wb3);
  route_kernel<<<64, 256, 0, stream>>>(m1, m2, m3, rw1, rw2, rw3, cnt, idxb, wgtb);

  moe_gemm<512, 256, 0, 0><<<dim3(CAP / 64, 8, 1), 256, 0, stream>>>(
      x, Wb1, b1, cnt + 0, idxb + 0, wgtb + 0, tmp1);
  moe_gemm<256, 256, 1, 0><<<dim3(CAP / 64, 8, 1), 256, 0, stream>>>(
      tmp1, Wb2, b2, cnt + 8, idxb + 8 * CAP, wgtb + 8 * CAP, tmp2);
  moe_gemm<256, 512, 1, 1><<<dim3(CAP / 64, 8, 2), 256, 0, stream>>>(
      tmp2, Wb3, b3, cnt + 16, idxb + 16 * CAP, wgtb + 16 * CAP, tmp3);

  finalize_kernel<<<4096, 256, 0, stream>>>(tmp3, out);
}

// Round 2
// 192.147 us; speedup vs baseline: 1.6969x; 1.6969x over previous
//
#include <hip/hip_runtime.h>

#define T_TOKENS 16384
#define CAP 12288     // per-expert bucket capacity; expected count ~4096
#define CNT_STRIDE 16 // one 64B cacheline per counter (parallel atomic streams)

typedef unsigned short u16;
typedef __attribute__((ext_vector_type(8))) short short8;
typedef __attribute__((ext_vector_type(4))) float float4v;

__device__ __forceinline__ u16 f2b(float f) {
  unsigned u = __float_as_uint(f);
  u = (u + 0x7fffu + ((u >> 16) & 1u)) >> 16;   // RNE fp32 -> bf16
  return (u16)u;
}
__device__ __forceinline__ float b2f(u16 h) {
  return __uint_as_float(((unsigned)h) << 16);
}

// ---------------- weight fp32 -> bf16 conversion ----------------
__global__ void convert_w(const float* __restrict__ W1, const float* __restrict__ W2,
                          const float* __restrict__ W3, u16* __restrict__ Wb1,
                          u16* __restrict__ Wb2, u16* __restrict__ Wb3) {
  const int n1 = 8 * 256 * 512, n2 = 8 * 256 * 256;
  int base = (blockIdx.x * 256 + threadIdx.x) * 8;
  const float* src;
  u16* dst;
  int off = base;
  if (base < n1) { src = W1; dst = Wb1; }
  else if (base < n1 + n2) { src = W2; dst = Wb2; off = base - n1; }
  else { src = W3; dst = Wb3; off = base - n1 - n2; }
  float4 a0 = *(const float4*)(src + off);
  float4 a1 = *(const float4*)(src + off + 4);
  short8 v;
  v[0] = (short)f2b(a0.x); v[1] = (short)f2b(a0.y);
  v[2] = (short)f2b(a0.z); v[3] = (short)f2b(a0.w);
  v[4] = (short)f2b(a1.x); v[5] = (short)f2b(a1.y);
  v[6] = (short)f2b(a1.z); v[7] = (short)f2b(a1.w);
  *(short8*)(dst + off) = v;
}

// ---------------- routing: two-phase block-local histogram + single atomic round ----------------
// Phase 1: LDS histogram of 24 (stage,expert) counters over this block's 256 tokens,
//          recording each (t,k)'s local position via LDS atomicAdd (~4cyc, no L2 round trip).
// Phase 2: threads 0..23 reserve global ranges with ONE parallel batch of global atomics.
// Phase 3: scatter (t*2+k, rw) into reserved slots.
__global__ void route_kernel(const int* __restrict__ m1, const int* __restrict__ m2,
                             const int* __restrict__ m3, const float* __restrict__ rw1,
                             const float* __restrict__ rw2, const float* __restrict__ rw3,
                             int* __restrict__ cnt, int* __restrict__ idxbuf,
                             float* __restrict__ wgtbuf) {
  __shared__ int lcnt[24];
  __shared__ int lbase[24];
  const int tid = threadIdx.x;
  const int t = blockIdx.x * 256 + tid;       // grid exactly covers T
  if (tid < 24) lcnt[tid] = 0;
  __syncthreads();

  const int* masks[3] = {m1, m2, m3};
  const float* rws[3] = {rw1, rw2, rw3};
  int expert[3][2], lpos[3][2];
#pragma unroll
  for (int s = 0; s < 3; ++s)
#pragma unroll
    for (int k = 0; k < 2; ++k) {
      int e = 0;
#pragma unroll
      for (int j = 0; j < 8; ++j)
        if (masks[s][(j * 2 + k) * T_TOKENS + t] != 0) e = j;
      expert[s][k] = e;
      lpos[s][k] = atomicAdd(&lcnt[s * 8 + e], 1);
    }
  __syncthreads();
  if (tid < 24) lbase[tid] = atomicAdd(&cnt[tid * CNT_STRIDE], lcnt[tid]);
  __syncthreads();
#pragma unroll
  for (int s = 0; s < 3; ++s)
#pragma unroll
    for (int k = 0; k < 2; ++k) {
      int e = expert[s][k];
      int p = lbase[s * 8 + e] + lpos[s][k];
      if (p < CAP) {
        idxbuf[(s * 8 + e) * CAP + p] = t * 2 + k;
        wgtbuf[(s * 8 + e) * CAP + p] = rws[s][t * 2 + k];
      }
    }
}

// ---------------- grouped gather-GEMM: 64 rows x 256 cols per block ----------------
// SRC==0: A rows gathered from fp32 x (row length KDIM), converted to bf16.
// SRC==1: A rows = bf16 tmpPrev[t][0][:] + tmpPrev[t][1][:] (fp32 add, re-round).
// Epilogue: out = w * (relu?)(dot + bias), scattered bf16 to outTmp[t*2+k][NDIM_TOTAL].
template <int KDIM, int NDIM_TOTAL, int SRC, int RELU>
__global__ __launch_bounds__(256) void moe_gemm(
    const void* __restrict__ Asrc, const u16* __restrict__ Wb, const float* __restrict__ bias,
    const int* __restrict__ cnt, const int* __restrict__ idxbuf, const float* __restrict__ wgtbuf,
    u16* __restrict__ outTmp) {
  __shared__ __align__(16) u16 As[64][72];    // +8 pad: bank-conflict break
  __shared__ __align__(16) u16 Bs[256][72];
  __shared__ int rowTok[64];
  __shared__ float rowW[64];

  const int e = blockIdx.y;
  const int n_e = cnt[e * CNT_STRIDE];
  const int row0 = blockIdx.x * 64;
  if (row0 >= n_e) return;
  const int nbase = blockIdx.z * 256;
  const int tid = threadIdx.x;

  if (tid < 64) {
    int g = row0 + tid;
    if (g < n_e) {
      rowTok[tid] = idxbuf[e * CAP + g];
      rowW[tid] = wgtbuf[e * CAP + g];
    } else {
      rowTok[tid] = 0;   // safe gather target; stores masked by g < n_e
      rowW[tid] = 0.f;
    }
  }
  __syncthreads();

  const int wave = tid >> 6, lane = tid & 63;
  const int lrow = lane & 15, lquad = lane >> 4;
  const int arow = tid >> 3;            // 0..31
  const int acol = (tid & 7) * 8;       // element offset, 16B granules

  float4v acc[4][4];
#pragma unroll
  for (int i = 0; i < 4; ++i)
#pragma unroll
    for (int j = 0; j < 4; ++j) acc[i][j] = (float4v)0.f;

  const u16* Wbe = Wb + ((size_t)e * NDIM_TOTAL + nbase) * KDIM;

  for (int kb = 0; kb < KDIM; kb += 64) {
    // ---- stage A tile (64 x 64) ----
#pragma unroll
    for (int it = 0; it < 2; ++it) {
      int r = arow + it * 32;
      int tok = rowTok[r];
      short8 v;
      if (SRC == 0) {
        const float* xp = (const float*)Asrc + (size_t)(tok >> 1) * KDIM + kb + acol;
        float4 a0 = *(const float4*)xp;
        float4 a1 = *(const float4*)(xp + 4);
        v[0] = (short)f2b(a0.x); v[1] = (short)f2b(a0.y);
        v[2] = (short)f2b(a0.z); v[3] = (short)f2b(a0.w);
        v[4] = (short)f2b(a1.x); v[5] = (short)f2b(a1.y);
        v[6] = (short)f2b(a1.z); v[7] = (short)f2b(a1.w);
      } else {
        const u16* p0 = (const u16*)Asrc + ((size_t)(tok >> 1) * 2) * KDIM + kb + acol;
        short8 v0 = *(const short8*)p0;
        short8 v1 = *(const short8*)(p0 + KDIM);
#pragma unroll
        for (int j = 0; j < 8; ++j)
          v[j] = (short)f2b(b2f((u16)v0[j]) + b2f((u16)v1[j]));
      }
      *(short8*)&As[r][acol] = v;
    }
    // ---- stage B tile (256 x 64) ----
#pragma unroll
    for (int it = 0; it < 8; ++it) {
      int r = arow + it * 32;
      *(short8*)&Bs[r][acol] = *(const short8*)(Wbe + (size_t)r * KDIM + kb + acol);
    }
    __syncthreads();
    // ---- MFMA ----
#pragma unroll
    for (int ks = 0; ks < 64; ks += 32) {
      short8 af[4], bfr[4];
#pragma unroll
      for (int mt = 0; mt < 4; ++mt)
        af[mt] = *(const short8*)&As[mt * 16 + lrow][ks + lquad * 8];
#pragma unroll
      for (int nt = 0; nt < 4; ++nt)
        bfr[nt] = *(const short8*)&Bs[wave * 64 + nt * 16 + lrow][ks + lquad * 8];
#pragma unroll
      for (int mt = 0; mt < 4; ++mt)
#pragma unroll
        for (int nt = 0; nt < 4; ++nt)
          acc[mt][nt] = __builtin_amdgcn_mfma_f32_16x16x32_bf16(af[mt], bfr[nt], acc[mt][nt], 0, 0, 0);
    }
    __syncthreads();
  }

  // ---- epilogue: w * (relu?)(dot + bias) -> scatter bf16 ----
  float bv[4];
#pragma unroll
  for (int nt = 0; nt < 4; ++nt)
    bv[nt] = bias[e * NDIM_TOTAL + nbase + wave * 64 + nt * 16 + lrow];
#pragma unroll
  for (int mt = 0; mt < 4; ++mt) {
#pragma unroll
    for (int i = 0; i < 4; ++i) {
      int m = mt * 16 + lquad * 4 + i;
      if (row0 + m < n_e) {
        float w = rowW[m];
        size_t drow = (size_t)rowTok[m] * NDIM_TOTAL + nbase;
#pragma unroll
        for (int nt = 0; nt < 4; ++nt) {
          float v = acc[mt][nt][i] + bv[nt];
          if (RELU) v = fmaxf(v, 0.f);
          v *= w;
          outTmp[drow + wave * 64 + nt * 16 + lrow] = f2b(v);
        }
      }
    }
  }
}

// ---------------- finalize: out = relu(tmp3[t][0] + tmp3[t][1]) ----------------
__global__ void finalize_kernel(const u16* __restrict__ tmp3, float* __restrict__ out) {
  int f = (blockIdx.x * 256 + threadIdx.x) * 8;
  int t = f >> 9;
  int o = f & 511;
  const u16* p = tmp3 + (size_t)t * 1024 + o;
  short8 v0 = *(const short8*)p;
  short8 v1 = *(const short8*)(p + 512);
  float4 r0, r1;
  r0.x = fmaxf(b2f((u16)v0[0]) + b2f((u16)v1[0]), 0.f);
  r0.y = fmaxf(b2f((u16)v0[1]) + b2f((u16)v1[1]), 0.f);
  r0.z = fmaxf(b2f((u16)v0[2]) + b2f((u16)v1[2]), 0.f);
  r0.w = fmaxf(b2f((u16)v0[3]) + b2f((u16)v1[3]), 0.f);
  r1.x = fmaxf(b2f((u16)v0[4]) + b2f((u16)v1[4]), 0.f);
  r1.y = fmaxf(b2f((u16)v0[5]) + b2f((u16)v1[5]), 0.f);
  r1.z = fmaxf(b2f((u16)v0[6]) + b2f((u16)v1[6]), 0.f);
  r1.w = fmaxf(b2f((u16)v0[7]) + b2f((u16)v1[7]), 0.f);
  *(float4*)(out + f) = r0;
  *(float4*)(out + f + 4) = r1;
}

extern "C" void kernel_launch(void* const* d_in, const int* in_sizes, int n_in,
                              void* d_out, int out_size, void* d_ws, size_t ws_size,
                              hipStream_t stream) {
  const float* x  = (const float*)d_in[0];
  const int* m1   = (const int*)d_in[1];
  const int* m2   = (const int*)d_in[2];
  const int* m3   = (const int*)d_in[3];
  const float* rw1 = (const float*)d_in[4];
  const float* rw2 = (const float*)d_in[5];
  const float* rw3 = (const float*)d_in[6];
  const float* W1 = (const float*)d_in[7];
  const float* b1 = (const float*)d_in[8];
  const float* W2 = (const float*)d_in[9];
  const float* b2 = (const float*)d_in[10];
  const float* W3 = (const float*)d_in[11];
  const float* b3 = (const float*)d_in[12];
  float* out = (float*)d_out;

  char* ws = (char*)d_ws;
  size_t off = 0;
  int* cnt = (int*)(ws + off); off += 24 * CNT_STRIDE * 4;
  u16* Wb1 = (u16*)(ws + off); off += (size_t)8 * 256 * 512 * 2;
  u16* Wb2 = (u16*)(ws + off); off += (size_t)8 * 256 * 256 * 2;
  u16* Wb3 = (u16*)(ws + off); off += (size_t)8 * 512 * 256 * 2;
  u16* tmp1 = (u16*)(ws + off); off += (size_t)T_TOKENS * 2 * 256 * 2;
  u16* tmp2 = (u16*)(ws + off); off += (size_t)T_TOKENS * 2 * 256 * 2;
  u16* tmp3 = (u16*)(ws + off); off += (size_t)T_TOKENS * 2 * 512 * 2;
  int* idxb = (int*)(ws + off); off += (size_t)3 * 8 * CAP * 4;
  float* wgtb = (float*)(ws + off); off += (size_t)3 * 8 * CAP * 4;

  hipMemsetAsync(cnt, 0, 24 * CNT_STRIDE * 4, stream);
  convert_w<<<1280, 256, 0, stream>>>(W1, W2, W3, Wb1, Wb2, Wb3);
  route_kernel<<<64, 256, 0, stream>>>(m1, m2, m3, rw1, rw2, rw3, cnt, idxb, wgtb);

  moe_gemm<512, 256, 0, 0><<<dim3(CAP / 64, 8, 1), 256, 0, stream>>>(
      x, Wb1, b1, cnt + 0, idxb + 0, wgtb + 0, tmp1);
  moe_gemm<256, 256, 1, 0><<<dim3(CAP / 64, 8, 1), 256, 0, stream>>>(
      tmp1, Wb2, b2, cnt + 8 * CNT_STRIDE, idxb + 8 * CAP, wgtb + 8 * CAP, tmp2);
  moe_gemm<256, 512, 1, 1><<<dim3(CAP / 64, 8, 2), 256, 0, stream>>>(
      tmp2, Wb3, b3, cnt + 16 * CNT_STRIDE, idxb + 16 * CAP, wgtb + 16 * CAP, tmp3);

  finalize_kernel<<<4096, 256, 0, stream>>>(tmp3, out);
}